// Round 9
// baseline (279.614 us; speedup 1.0000x reference)
//
#include <hip/hip_runtime.h>
#include <float.h>
#include <stdint.h>

// SOM2D argmin ||x-w||^2 via split-f16 MFMA. N=32768, M=4096, D=128.
//
// score = ||w||^2 - 2 x.w  (||x||^2 constant per sample: dropped)
// cross = xh*wh + xl*wh + xh*wl  (f16 hi/lo split, fp32 accum; |err|~2e-5)
//
// Round-9: occupancy-first redesign (R6-R8 showed 2 waves/SIMD + source-level
// scheduling is a dead end; the binder is L1 batch queueing, not bandwidth).
//  - m=32/wave: Ah+Al BOTH register-resident (64 VGPRs) -> zero A traffic.
//    acc=16 regs (-> AGPRs under pressure). Fits the compiler's 128-reg target.
//  - B-hi via LDS double-buffer (16 KB, ONE barrier/tile, cooperative staging);
//    B-lo direct from L1. Split routes: LDS ~25us, L1 ~33us, MFMA ~47-50us.
//  - __launch_bounds__(256,4): 4 blocks/CU = 4 waves/SIMD (2x all prior TLP).
//  - grid = 256 sample-groups x UG=4 unit-groups = 1024 blocks = exact 4/CU.

constexpr int D = 128;

typedef _Float16 f16x8 __attribute__((ext_vector_type(8)));
typedef float    f32x4 __attribute__((ext_vector_type(4)));

__device__ __forceinline__ void cvt_split(const float4& a0, const float4& a1,
                                          f16x8& h, f16x8& l) {
    float v[8] = {a0.x, a0.y, a0.z, a0.w, a1.x, a1.y, a1.z, a1.w};
#pragma unroll
    for (int j = 0; j < 8; ++j) {
        _Float16 hh = (_Float16)v[j];
        h[j] = hh;
        l[j] = (_Float16)(v[j] - (float)hh);
    }
}

// W (M x D fp32) -> frag-major hi/lo f16 + wsq; zeroes group counters.
// Granule slot for (u, k=8o..8o+7), n-tile = 32 units:
//   T=u>>5, t=(u>>4)&1, c=u&15, s=o>>2, q=o&3
//   slot = T*512 + s*128 + t*64 + q*16 + c      (f16x8 granules)
// Per tile the 512 granules are contiguous -> staging is a flat memcpy.
__global__ __launch_bounds__(256) void prep_kernel(
        const float* __restrict__ w, f16x8* __restrict__ hG,
        f16x8* __restrict__ lG, float* __restrict__ wsq,
        int* __restrict__ cnt, int nGroups, int M) {
    if (cnt && blockIdx.x == 0 && (int)threadIdx.x < nGroups) cnt[threadIdx.x] = 0;
    int g = blockIdx.x * 256 + threadIdx.x;
    if (g >= M * 16) return;
    int u = g >> 4, o = g & 15;
    const float4* wp = reinterpret_cast<const float4*>(w + (size_t)u * D + o * 8);
    float4 a0 = wp[0], a1 = wp[1];
    f16x8 h, l;
    cvt_split(a0, a1, h, l);
    float ss = 0.f;
    ss = fmaf(a0.x, a0.x, ss); ss = fmaf(a0.y, a0.y, ss);
    ss = fmaf(a0.z, a0.z, ss); ss = fmaf(a0.w, a0.w, ss);
    ss = fmaf(a1.x, a1.x, ss); ss = fmaf(a1.y, a1.y, ss);
    ss = fmaf(a1.z, a1.z, ss); ss = fmaf(a1.w, a1.w, ss);
#pragma unroll
    for (int m = 1; m < 16; m <<= 1) ss += __shfl_xor(ss, m, 64);
    if (o == 0) wsq[u] = ss;
    int slot = ((u >> 5) << 9) + ((o >> 2) << 7) + (((u >> 4) & 1) << 6)
             + ((o & 3) << 4) + (u & 15);
    hG[slot] = h;
    lG[slot] = l;
}

template <bool PARTIAL>
__global__ __launch_bounds__(256, 4) void som_main(
        const float* __restrict__ x, const f16x8* __restrict__ hG,
        const f16x8* __restrict__ lG, const float* __restrict__ wsq,
        const int* __restrict__ grid, int* __restrict__ out,
        unsigned long long* __restrict__ keys, int* __restrict__ cnt,
        int unitGroups, int M, int N) {
    __shared__ f16x8 bbuf[2][512];   // B-hi double buffer, 16 KB total
    __shared__ int lastFlag;

    const int tid  = threadIdx.x;
    const int lane = tid & 63;
    const int wv   = tid >> 6;
    const int c    = lane & 15;   // frag col-class
    const int q    = lane >> 4;   // frag quad

    const int ug    = blockIdx.x % unitGroups;
    const int sg    = blockIdx.x / unitGroups;
    const int sWave = sg * 128 + wv * 32;   // this wave's 32 samples

    // ---- A-frags: 32 samples x K=128, hi AND lo register-resident (64 VGPRs).
    // A[m = lane&15][k = q*8 + j], m-tile i in {0,1}, k-step s in 0..3.
    f16x8 Ah[8], Al[8];
#pragma unroll
    for (int i = 0; i < 2; ++i) {
        const float* xr = x + (size_t)(sWave + 16 * i + c) * D + q * 8;
#pragma unroll
        for (int s = 0; s < 4; ++s) {
            float4 a0 = *reinterpret_cast<const float4*>(xr + 32 * s);
            float4 a1 = *reinterpret_cast<const float4*>(xr + 32 * s + 4);
            cvt_split(a0, a1, Ah[i * 4 + s], Al[i * 4 + s]);
        }
    }

    float bestD[8];
    int   bestI[8];
#pragma unroll
    for (int sl = 0; sl < 8; ++sl) { bestD[sl] = FLT_MAX; bestI[sl] = 0; }

    const int tilesPer = (M / 32) / unitGroups;
    const int tile0    = ug * tilesPer;

    // ---- preload tile0's hi into staging regs ----
    f16x8 st0, st1;
    {
        const f16x8* hs = hG + ((size_t)tile0 << 9);
        st0 = hs[tid];
        st1 = hs[tid + 256];
    }

    for (int tt = 0; tt < tilesPer; ++tt) {
        const int tile = tile0 + tt;
        const int buf  = tt & 1;

        // commit staged hi-tile to LDS; single barrier per tile.
        bbuf[buf][tid]       = st0;
        bbuf[buf][tid + 256] = st1;
        __syncthreads();

        // issue NEXT tile's hi loads now (consumed at next iteration's writes;
        // latency covered by this tile's compute).
        if (tt + 1 < tilesPer) {
            const f16x8* hn = hG + ((size_t)(tile + 1) << 9);
            st0 = hn[tid];
            st1 = hn[tid + 256];
        }

        const f16x8* lp = lG + ((size_t)tile << 9) + lane;   // B-lo via L1
        const int uTile = tile * 32;
        const float wq0 = wsq[uTile + c];
        const float wq1 = wsq[uTile + 16 + c];

        f32x4 acc[4];   // [i*2 + t]
#pragma unroll
        for (int f = 0; f < 4; ++f) acc[f] = (f32x4){0.f, 0.f, 0.f, 0.f};

#pragma unroll
        for (int s = 0; s < 4; ++s) {
            f16x8 b0 = bbuf[buf][s * 128 + lane];        // hi, t=0 (LDS)
            f16x8 b1 = bbuf[buf][s * 128 + 64 + lane];   // hi, t=1 (LDS)
            f16x8 l0 = lp[s * 128];                      // lo, t=0 (L1)
            f16x8 l1 = lp[s * 128 + 64];                 // lo, t=1 (L1)
            // pass 1: xh.wh
#pragma unroll
            for (int i = 0; i < 2; ++i) {
                acc[i * 2 + 0] = __builtin_amdgcn_mfma_f32_16x16x32_f16(
                    Ah[i * 4 + s], b0, acc[i * 2 + 0], 0, 0, 0);
                acc[i * 2 + 1] = __builtin_amdgcn_mfma_f32_16x16x32_f16(
                    Ah[i * 4 + s], b1, acc[i * 2 + 1], 0, 0, 0);
            }
            // pass 2: xl.wh
#pragma unroll
            for (int i = 0; i < 2; ++i) {
                acc[i * 2 + 0] = __builtin_amdgcn_mfma_f32_16x16x32_f16(
                    Al[i * 4 + s], b0, acc[i * 2 + 0], 0, 0, 0);
                acc[i * 2 + 1] = __builtin_amdgcn_mfma_f32_16x16x32_f16(
                    Al[i * 4 + s], b1, acc[i * 2 + 1], 0, 0, 0);
            }
            // pass 3: xh.wl
#pragma unroll
            for (int i = 0; i < 2; ++i) {
                acc[i * 2 + 0] = __builtin_amdgcn_mfma_f32_16x16x32_f16(
                    Ah[i * 4 + s], l0, acc[i * 2 + 0], 0, 0, 0);
                acc[i * 2 + 1] = __builtin_amdgcn_mfma_f32_16x16x32_f16(
                    Ah[i * 4 + s], l1, acc[i * 2 + 1], 0, 0, 0);
            }
        }

        // ---- score + per-lane argmin. C layout: row m = 16i + q*4+r, col = c+16t.
#pragma unroll
        for (int t = 0; t < 2; ++t) {
            const int n    = uTile + 16 * t + c;
            const float wq = t == 0 ? wq0 : wq1;
#pragma unroll
            for (int i = 0; i < 2; ++i) {
                f32x4 a = acc[i * 2 + t];
#pragma unroll
                for (int r = 0; r < 4; ++r) {
                    float score = fmaf(-2.f, a[r], wq);
                    int sl = i * 4 + r;
                    if (score < bestD[sl]) { bestD[sl] = score; bestI[sl] = n; }
                }
            }
        }
    }

    // ---- reduce over the 16 col-classes (xor within each 16-lane q-group) ----
#pragma unroll
    for (int sl = 0; sl < 8; ++sl) {
        float d   = bestD[sl];
        int   idx = bestI[sl];
#pragma unroll
        for (int m = 1; m < 16; m <<= 1) {
            float od = __shfl_xor(d, m, 64);
            int   oi = __shfl_xor(idx, m, 64);
            if (od < d || (od == d && oi < idx)) { d = od; idx = oi; }
        }
        if (c == 0) {
            const int sOut = sWave + 16 * (sl >> 2) + 4 * q + (sl & 3);
            if (PARTIAL) {
                unsigned ub = __float_as_uint(d);
                ub = (ub & 0x80000000u) ? ~ub : (ub | 0x80000000u);  // monotone map
                unsigned long long key = ((unsigned long long)ub << 32) | (unsigned)idx;
                keys[(size_t)ug * N + sOut] = key;
            } else {
                out[2 * sOut]     = grid[2 * idx];
                out[2 * sOut + 1] = grid[2 * idx + 1];
            }
        }
    }

    // ---- fused finalize: last block of this sample-group reduces partials ----
    if (PARTIAL) {
        __threadfence();          // release: make this block's keys visible
        __syncthreads();          // all waves' keys written + fenced
        if (tid == 0) {
            int old = atomicAdd(&cnt[sg], 1);
            lastFlag = (old == unitGroups - 1);
        }
        __syncthreads();
        if (lastFlag) {
            __threadfence();      // acquire: see other blocks' keys
            if (tid < 128) {
                const int s = sg * 128 + tid;
                unsigned long long k = keys[s];
                for (int g = 1; g < unitGroups; ++g) {
                    unsigned long long kg = keys[(size_t)g * N + s];
                    if (kg < k) k = kg;   // equal dist -> lower idx
                }
                const int idx = (int)(unsigned)(k & 0xFFFFFFFFull);
                out[2 * s]     = grid[2 * idx];
                out[2 * s + 1] = grid[2 * idx + 1];
            }
        }
    }
}

extern "C" void kernel_launch(void* const* d_in, const int* in_sizes, int n_in,
                              void* d_out, int out_size, void* d_ws, size_t ws_size,
                              hipStream_t stream) {
    const float* x    = (const float*)d_in[0];
    const float* w    = (const float*)d_in[1];
    const int*   grid = (const int*)d_in[2];
    int* out = (int*)d_out;

    const int N = in_sizes[0] / D;   // 32768
    const int M = in_sizes[1] / D;   // 4096
    const int nGroups = N / 128;     // 256 sample-groups (128 samples/block)

    // ws layout: hG (1 MB) | lG (1 MB) | wsq (16 KB) | keys (UG*N*8) | cnt
    const size_t hlBytes   = (size_t)M * D * 2;
    const size_t baseBytes = 2 * hlBytes + (size_t)M * 4;

    f16x8* hG  = (f16x8*)d_ws;
    f16x8* lG  = (f16x8*)((char*)d_ws + hlBytes);
    float* wsq = (float*)((char*)d_ws + 2 * hlBytes);

    int UG = 0;
    if (ws_size >= baseBytes + 4ull * N * 8 + (size_t)nGroups * 4) UG = 4;
    else if (ws_size >= baseBytes + 2ull * N * 8 + (size_t)nGroups * 4) UG = 2;

    unsigned long long* keys = (unsigned long long*)((char*)d_ws + baseBytes);
    int* cnt = (int*)((char*)d_ws + baseBytes + (size_t)UG * N * 8);

    prep_kernel<<<(M * 16 + 255) / 256, 256, 0, stream>>>(
        w, hG, lG, wsq, UG > 0 ? cnt : nullptr, nGroups, M);

    if (UG > 0) {
        som_main<true><<<nGroups * UG, 256, 0, stream>>>(
            x, hG, lG, wsq, grid, out, keys, cnt, UG, M, N);
    } else {
        som_main<false><<<nGroups, 256, 0, stream>>>(
            x, hG, lG, wsq, grid, out, nullptr, nullptr, 1, M, N);
    }
}

// Round 10
// 241.547 us; speedup vs baseline: 1.1576x; 1.1576x over previous
//
#include <hip/hip_runtime.h>
#include <float.h>
#include <stdint.h>

// SOM2D argmin ||x-w||^2 via split-f16 MFMA. N=32768, M=4096, D=128.
//
// score = ||w||^2 - 2 x.w  (||x||^2 constant per sample: dropped)
// cross = xh*wh + xl*wh + xh*wl  (f16 hi/lo split, fp32 accum; |err|~2e-5)
//
// Round-10: R6 was L1-BOUND (model fits: 4 waves/block each pulling the same
// 16 KB B-tile through L1 = 2048 cyc/tile/CU vs MFMA 932 -> 2.2x floor =
// the measured 98.8us). Fix: stage B (hi AND lo) in LDS ONCE PER BLOCK.
//   per tile/CU: L1 512 cyc (staging only), LDS ~430 cyc/SIMD, MFMA 932 ->
//   compute-bound. Everything else is the proven R5/R6 recipe: m=64/wave,
//   Ah+Al register/AGPR-resident (allocator handled this in R5), plain
//   launch_bounds(256), JIT LDS reads (LDS latency ~120cyc is coverable),
//   one barrier/tile, 32 KB double buffer, prefetch issued AFTER the barrier.

constexpr int D = 128;

typedef _Float16 f16x8 __attribute__((ext_vector_type(8)));
typedef float    f32x4 __attribute__((ext_vector_type(4)));

__device__ __forceinline__ void cvt_split(const float4& a0, const float4& a1,
                                          f16x8& h, f16x8& l) {
    float v[8] = {a0.x, a0.y, a0.z, a0.w, a1.x, a1.y, a1.z, a1.w};
#pragma unroll
    for (int j = 0; j < 8; ++j) {
        _Float16 hh = (_Float16)v[j];
        h[j] = hh;
        l[j] = (_Float16)(v[j] - (float)hh);
    }
}

// W (M x D fp32) -> frag-major hi/lo f16 + wsq; zeroes group counters.
// Granule slot for (u, k=8o..8o+7), n-tile = 32 units:
//   T=u>>5, t=(u>>4)&1, c=u&15, s=o>>2, q=o&3
//   slot = T*512 + s*128 + t*64 + q*16 + c      (f16x8 granules)
// Per tile the 512 granules are contiguous -> staging is a flat memcpy.
__global__ __launch_bounds__(256) void prep_kernel(
        const float* __restrict__ w, f16x8* __restrict__ hG,
        f16x8* __restrict__ lG, float* __restrict__ wsq,
        int* __restrict__ cnt, int nGroups, int M) {
    if (cnt && blockIdx.x == 0 && (int)threadIdx.x < nGroups) cnt[threadIdx.x] = 0;
    int g = blockIdx.x * 256 + threadIdx.x;
    if (g >= M * 16) return;
    int u = g >> 4, o = g & 15;
    const float4* wp = reinterpret_cast<const float4*>(w + (size_t)u * D + o * 8);
    float4 a0 = wp[0], a1 = wp[1];
    f16x8 h, l;
    cvt_split(a0, a1, h, l);
    float ss = 0.f;
    ss = fmaf(a0.x, a0.x, ss); ss = fmaf(a0.y, a0.y, ss);
    ss = fmaf(a0.z, a0.z, ss); ss = fmaf(a0.w, a0.w, ss);
    ss = fmaf(a1.x, a1.x, ss); ss = fmaf(a1.y, a1.y, ss);
    ss = fmaf(a1.z, a1.z, ss); ss = fmaf(a1.w, a1.w, ss);
#pragma unroll
    for (int m = 1; m < 16; m <<= 1) ss += __shfl_xor(ss, m, 64);
    if (o == 0) wsq[u] = ss;
    int slot = ((u >> 5) << 9) + ((o >> 2) << 7) + (((u >> 4) & 1) << 6)
             + ((o & 3) << 4) + (u & 15);
    hG[slot] = h;
    lG[slot] = l;
}

template <bool PARTIAL>
__global__ __launch_bounds__(256) void som_main(
        const float* __restrict__ x, const f16x8* __restrict__ hG,
        const f16x8* __restrict__ lG, const float* __restrict__ wsq,
        const int* __restrict__ grid, int* __restrict__ out,
        unsigned long long* __restrict__ keys, int* __restrict__ cnt,
        int unitGroups, int M, int N) {
    __shared__ f16x8 hbuf[2][512];   // B-hi double buffer (16 KB)
    __shared__ f16x8 lbuf[2][512];   // B-lo double buffer (16 KB)
    __shared__ int lastFlag;

    const int tid  = threadIdx.x;
    const int lane = tid & 63;
    const int wv   = tid >> 6;
    const int c    = lane & 15;   // frag col-class
    const int q    = lane >> 4;   // frag quad

    const int ug    = blockIdx.x % unitGroups;
    const int sg    = blockIdx.x / unitGroups;
    const int sWave = sg * 256 + wv * 64;   // this wave's 64 samples

    // ---- A-frags: 64 samples x K=128, hi+lo resident (128 regs; allocator
    // may park the pass-2-only Al in AGPRs — legal MFMA A-operands on gfx950).
    // A[m = lane&15][k = q*8 + j], m-tile i in 0..3, k-step s in 0..3.
    f16x8 Ah[16], Al[16];
#pragma unroll
    for (int i = 0; i < 4; ++i) {
        const float* xr = x + (size_t)(sWave + 16 * i + c) * D + q * 8;
#pragma unroll
        for (int s = 0; s < 4; ++s) {
            float4 a0 = *reinterpret_cast<const float4*>(xr + 32 * s);
            float4 a1 = *reinterpret_cast<const float4*>(xr + 32 * s + 4);
            cvt_split(a0, a1, Ah[i * 4 + s], Al[i * 4 + s]);
        }
    }

    float bestD[16];
    int   bestI[16];
#pragma unroll
    for (int sl = 0; sl < 16; ++sl) { bestD[sl] = FLT_MAX; bestI[sl] = 0; }

    const int tilesPer = (M / 32) / unitGroups;
    const int tile0    = ug * tilesPer;

    // ---- preload tile0's B into staging regs (4+4 granules/thread) ----
    f16x8 sth0, sth1, stl0, stl1;
    {
        const f16x8* hp = hG + ((size_t)tile0 << 9);
        const f16x8* lp = lG + ((size_t)tile0 << 9);
        sth0 = hp[tid]; sth1 = hp[tid + 256];
        stl0 = lp[tid]; stl1 = lp[tid + 256];
    }

    for (int tt = 0; tt < tilesPer; ++tt) {
        const int tile = tile0 + tt;
        const int buf  = tt & 1;

        // commit staged tile to LDS; ONE barrier per tile.
        // (safe: reaching tile t's barrier implies every wave finished tile
        //  t-1's reads, so t+1's writes to buf^1 cannot race them.)
        hbuf[buf][tid] = sth0; hbuf[buf][tid + 256] = sth1;
        lbuf[buf][tid] = stl0; lbuf[buf][tid + 256] = stl1;
        __syncthreads();

        // prefetch NEXT tile AFTER the barrier (the barrier's vmcnt(0) drain
        // can't touch it; it has the whole ~2000cyc compute section to land).
        if (tt + 1 < tilesPer) {
            const f16x8* hn = hG + ((size_t)(tile + 1) << 9);
            const f16x8* ln = lG + ((size_t)(tile + 1) << 9);
            sth0 = hn[tid]; sth1 = hn[tid + 256];
            stl0 = ln[tid]; stl1 = ln[tid + 256];
        }

        const int uTile = tile * 32;
        const float wq0 = wsq[uTile + c];
        const float wq1 = wsq[uTile + 16 + c];

        f32x4 acc[8];   // [i*2 + t]
#pragma unroll
        for (int f = 0; f < 8; ++f) acc[f] = (f32x4){0.f, 0.f, 0.f, 0.f};

#pragma unroll
        for (int s = 0; s < 4; ++s) {
            // JIT LDS reads (R6-proven: ~120cyc LDS latency is coverable)
            f16x8 b0 = hbuf[buf][s * 128 + lane];
            f16x8 b1 = hbuf[buf][s * 128 + 64 + lane];
            f16x8 l0 = lbuf[buf][s * 128 + lane];
            f16x8 l1 = lbuf[buf][s * 128 + 64 + lane];
            // pass 1: xh.wh
#pragma unroll
            for (int i = 0; i < 4; ++i) {
                acc[i * 2 + 0] = __builtin_amdgcn_mfma_f32_16x16x32_f16(
                    Ah[i * 4 + s], b0, acc[i * 2 + 0], 0, 0, 0);
                acc[i * 2 + 1] = __builtin_amdgcn_mfma_f32_16x16x32_f16(
                    Ah[i * 4 + s], b1, acc[i * 2 + 1], 0, 0, 0);
            }
            // pass 2: xl.wh
#pragma unroll
            for (int i = 0; i < 4; ++i) {
                acc[i * 2 + 0] = __builtin_amdgcn_mfma_f32_16x16x32_f16(
                    Al[i * 4 + s], b0, acc[i * 2 + 0], 0, 0, 0);
                acc[i * 2 + 1] = __builtin_amdgcn_mfma_f32_16x16x32_f16(
                    Al[i * 4 + s], b1, acc[i * 2 + 1], 0, 0, 0);
            }
            // pass 3: xh.wl
#pragma unroll
            for (int i = 0; i < 4; ++i) {
                acc[i * 2 + 0] = __builtin_amdgcn_mfma_f32_16x16x32_f16(
                    Ah[i * 4 + s], l0, acc[i * 2 + 0], 0, 0, 0);
                acc[i * 2 + 1] = __builtin_amdgcn_mfma_f32_16x16x32_f16(
                    Ah[i * 4 + s], l1, acc[i * 2 + 1], 0, 0, 0);
            }
        }

        // ---- score + per-lane argmin. C layout: row m = 16i + q*4+r, col = c+16t.
#pragma unroll
        for (int t = 0; t < 2; ++t) {
            const int n    = uTile + 16 * t + c;
            const float wq = t == 0 ? wq0 : wq1;
#pragma unroll
            for (int i = 0; i < 4; ++i) {
                f32x4 a = acc[i * 2 + t];
#pragma unroll
                for (int r = 0; r < 4; ++r) {
                    float score = fmaf(-2.f, a[r], wq);
                    int sl = i * 4 + r;
                    if (score < bestD[sl]) { bestD[sl] = score; bestI[sl] = n; }
                }
            }
        }
    }

    // ---- reduce over the 16 col-classes (xor within each 16-lane q-group) ----
#pragma unroll
    for (int sl = 0; sl < 16; ++sl) {
        float d   = bestD[sl];
        int   idx = bestI[sl];
#pragma unroll
        for (int m = 1; m < 16; m <<= 1) {
            float od = __shfl_xor(d, m, 64);
            int   oi = __shfl_xor(idx, m, 64);
            if (od < d || (od == d && oi < idx)) { d = od; idx = oi; }
        }
        if (c == 0) {
            const int sOut = sWave + 16 * (sl >> 2) + 4 * q + (sl & 3);
            if (PARTIAL) {
                unsigned ub = __float_as_uint(d);
                ub = (ub & 0x80000000u) ? ~ub : (ub | 0x80000000u);  // monotone map
                unsigned long long key = ((unsigned long long)ub << 32) | (unsigned)idx;
                keys[(size_t)ug * N + sOut] = key;
            } else {
                out[2 * sOut]     = grid[2 * idx];
                out[2 * sOut + 1] = grid[2 * idx + 1];
            }
        }
    }

    // ---- fused finalize: last block of this sample-group reduces partials ----
    if (PARTIAL) {
        __threadfence();          // release: make this block's keys visible
        __syncthreads();          // all waves' keys written + fenced
        if (tid == 0) {
            int old = atomicAdd(&cnt[sg], 1);
            lastFlag = (old == unitGroups - 1);
        }
        __syncthreads();
        if (lastFlag) {
            __threadfence();      // acquire: see other blocks' keys
            const int s = sg * 256 + tid;
            unsigned long long k = keys[s];
            for (int g = 1; g < unitGroups; ++g) {
                unsigned long long kg = keys[(size_t)g * N + s];
                if (kg < k) k = kg;   // equal dist -> lower idx (smaller key)
            }
            const int idx = (int)(unsigned)(k & 0xFFFFFFFFull);
            out[2 * s]     = grid[2 * idx];
            out[2 * s + 1] = grid[2 * idx + 1];
        }
    }
}

extern "C" void kernel_launch(void* const* d_in, const int* in_sizes, int n_in,
                              void* d_out, int out_size, void* d_ws, size_t ws_size,
                              hipStream_t stream) {
    const float* x    = (const float*)d_in[0];
    const float* w    = (const float*)d_in[1];
    const int*   grid = (const int*)d_in[2];
    int* out = (int*)d_out;

    const int N = in_sizes[0] / D;   // 32768
    const int M = in_sizes[1] / D;   // 4096
    const int nGroups = N / 256;     // 128 sample-groups (256 samples/block)

    // ws layout: hG (1 MB) | lG (1 MB) | wsq (16 KB) | keys (UG*N*8) | cnt
    const size_t hlBytes   = (size_t)M * D * 2;
    const size_t baseBytes = 2 * hlBytes + (size_t)M * 4;

    f16x8* hG  = (f16x8*)d_ws;
    f16x8* lG  = (f16x8*)((char*)d_ws + hlBytes);
    float* wsq = (float*)((char*)d_ws + 2 * hlBytes);

    int UG = 0;
    if (ws_size >= baseBytes + 4ull * N * 8 + (size_t)nGroups * 4) UG = 4;
    else if (ws_size >= baseBytes + 2ull * N * 8 + (size_t)nGroups * 4) UG = 2;

    unsigned long long* keys = (unsigned long long*)((char*)d_ws + baseBytes);
    int* cnt = (int*)((char*)d_ws + baseBytes + (size_t)UG * N * 8);

    prep_kernel<<<(M * 16 + 255) / 256, 256, 0, stream>>>(
        w, hG, lG, wsq, UG > 0 ? cnt : nullptr, nGroups, M);

    if (UG > 0) {
        som_main<true><<<nGroups * UG, 256, 0, stream>>>(
            x, hG, lG, wsq, grid, out, keys, cnt, UG, M, N);
    } else {
        som_main<false><<<nGroups, 256, 0, stream>>>(
            x, hG, lG, wsq, grid, out, nullptr, nullptr, 1, M, N);
    }
}

// Round 11
// 156.071 us; speedup vs baseline: 1.7916x; 1.5477x over previous
//
#include <hip/hip_runtime.h>
#include <float.h>
#include <stdint.h>

// SOM2D argmin ||x-w||^2 via split-f16 MFMA. N=32768, M=4096, D=128.
//
// score = ||w||^2 - 2 x.w  (||x||^2 constant per sample: dropped)
// cross = xh*wh + xl*wh + xh*wl  (f16 hi/lo split, fp32 accum; |err|~2e-5)
//
// Round-11: EXACT restore of the Round-6 kernel (best: 98.8us main, 153.6us
// wall, MfmaUtil 44%, VGPR 120, 2 waves/SIMD). R7-R10 established that every
// deviation — register-recycling prefetch, occupancy attributes, LDS B-staging,
// full A-residency — is defeated by the register allocator (unified VGPR+AGPR
// budget) and regresses 1.4-2.3x. Structure:
//  - m=64/wave: Ah resident (64 VGPRs); Al in wave-private LDS (16 KB/wave,
//    no barriers, conflict-free).
//  - B pre-split frag-major in ws; whole tile (16 granules) batch-loaded to
//    regs before the 96-MFMA burst; L2-latency exposed once per ~1900 cyc.
//  - UG=4 unit-groups; partial argmin keys; separate finalize kernel.

constexpr int D = 128;

typedef _Float16 f16x8 __attribute__((ext_vector_type(8)));
typedef float    f32x4 __attribute__((ext_vector_type(4)));

__device__ __forceinline__ void cvt_split(const float4& a0, const float4& a1,
                                          f16x8& h, f16x8& l) {
    float v[8] = {a0.x, a0.y, a0.z, a0.w, a1.x, a1.y, a1.z, a1.w};
#pragma unroll
    for (int j = 0; j < 8; ++j) {
        _Float16 hh = (_Float16)v[j];
        h[j] = hh;
        l[j] = (_Float16)(v[j] - (float)hh);
    }
}

// W (M x D fp32) -> frag-major hi/lo f16 + wsq. Thread = (unit u, k-octet o).
// Granule slot for (u, k=8o..8o+7), n-tile = 32 units:
//   T=u>>5, t=(u>>4)&1, c=u&15, s=o>>2, q=o&3
//   slot = T*512 + s*128 + t*64 + q*16 + c
// Main-loop read: tile_base(T*512) + s*128 + t*64 + lane. Sequential 1KB/instr.
__global__ __launch_bounds__(256) void prep_kernel(
        const float* __restrict__ w, f16x8* __restrict__ hG,
        f16x8* __restrict__ lG, float* __restrict__ wsq, int M) {
    int g = blockIdx.x * 256 + threadIdx.x;
    if (g >= M * 16) return;
    int u = g >> 4, o = g & 15;
    const float4* wp = reinterpret_cast<const float4*>(w + (size_t)u * D + o * 8);
    float4 a0 = wp[0], a1 = wp[1];
    f16x8 h, l;
    cvt_split(a0, a1, h, l);
    float ss = 0.f;
    ss = fmaf(a0.x, a0.x, ss); ss = fmaf(a0.y, a0.y, ss);
    ss = fmaf(a0.z, a0.z, ss); ss = fmaf(a0.w, a0.w, ss);
    ss = fmaf(a1.x, a1.x, ss); ss = fmaf(a1.y, a1.y, ss);
    ss = fmaf(a1.z, a1.z, ss); ss = fmaf(a1.w, a1.w, ss);
#pragma unroll
    for (int m = 1; m < 16; m <<= 1) ss += __shfl_xor(ss, m, 64);
    if (o == 0) wsq[u] = ss;
    int slot = ((u >> 5) << 9) + ((o >> 2) << 7) + (((u >> 4) & 1) << 6)
             + ((o & 3) << 4) + (u & 15);
    hG[slot] = h;
    lG[slot] = l;
}

__global__ void finalize(const unsigned long long* __restrict__ keys,
                         const int* __restrict__ grid, int* __restrict__ out,
                         int N, int UG) {
    int s = blockIdx.x * blockDim.x + threadIdx.x;
    if (s >= N) return;
    unsigned long long k = keys[s];
    for (int g = 1; g < UG; ++g) {
        unsigned long long kg = keys[(size_t)g * N + s];
        if (kg < k) k = kg;   // equal dist -> lower idx (smaller key)
    }
    int idx = (int)(unsigned)(k & 0xFFFFFFFFull);
    out[2 * s]     = grid[2 * idx];
    out[2 * s + 1] = grid[2 * idx + 1];
}

template <bool PARTIAL>
__global__ __launch_bounds__(256, 2) void som_main(
        const float* __restrict__ x, const f16x8* __restrict__ hG,
        const f16x8* __restrict__ lG, const float* __restrict__ wsq,
        const int* __restrict__ grid, int* __restrict__ out,
        unsigned long long* __restrict__ keys,
        int unitGroups, int M, int N) {
    // Al (x-lo A-frags), wave-private: wave wv owns albuf[wv*1024 .. +1024)
    __shared__ f16x8 albuf[4 * 1024];   // 64 KB

    const int tid  = threadIdx.x;
    const int lane = tid & 63;
    const int wv   = tid >> 6;
    const int c    = lane & 15;   // frag col-class
    const int q    = lane >> 4;   // frag quad

    const int ug    = blockIdx.x % unitGroups;
    const int sg    = blockIdx.x / unitGroups;
    const int sWave = sg * 256 + wv * 64;   // this wave's 64 samples

    f16x8* myAl = &albuf[wv * 1024];

    // ---- A-frags: 64 samples x K=128. Ah resident (64 VGPRs); Al -> LDS.
    // A[m = lane&15][k = q*8 + j], m-tile i in 0..3, k-step s in 0..3.
    f16x8 Ah[16];
#pragma unroll
    for (int i = 0; i < 4; ++i) {
        const float* xr = x + (size_t)(sWave + 16 * i + c) * D + q * 8;
#pragma unroll
        for (int s = 0; s < 4; ++s) {
            float4 a0 = *reinterpret_cast<const float4*>(xr + 32 * s);
            float4 a1 = *reinterpret_cast<const float4*>(xr + 32 * s + 4);
            f16x8 h, l;
            cvt_split(a0, a1, h, l);
            Ah[i * 4 + s] = h;
            myAl[(i * 4 + s) * 64 + lane] = l;   // own slice only: no barrier
        }
    }

    float bestD[16];
    int   bestI[16];
#pragma unroll
    for (int sl = 0; sl < 16; ++sl) { bestD[sl] = FLT_MAX; bestI[sl] = 0; }

    const int tilesPer = (M / 32) / unitGroups;
    const int tile0    = ug * tilesPer;

    for (int tt = 0; tt < tilesPer; ++tt) {
        const int tile = tile0 + tt;
        const f16x8* hp = hG + ((size_t)tile << 9) + lane;
        const f16x8* lp = lG + ((size_t)tile << 9) + lane;

        // ---- hoist the ENTIRE tile's B into registers before the MFMA burst.
        // bh first (pass 1+2 operands land first), then bl (pass 3).
        f16x8 bh[8], bl[8];
#pragma unroll
        for (int s = 0; s < 4; ++s)
#pragma unroll
            for (int t = 0; t < 2; ++t)
                bh[s * 2 + t] = hp[s * 128 + t * 64];
#pragma unroll
        for (int s = 0; s < 4; ++s)
#pragma unroll
            for (int t = 0; t < 2; ++t)
                bl[s * 2 + t] = lp[s * 128 + t * 64];

        const int uTile = tile * 32;
        const float wq0 = wsq[uTile + c];
        const float wq1 = wsq[uTile + 16 + c];

        f32x4 acc[8];   // [i*2 + t]
#pragma unroll
        for (int f = 0; f < 8; ++f) acc[f] = (f32x4){0.f, 0.f, 0.f, 0.f};

        // pass 1: xh.wh
#pragma unroll
        for (int s = 0; s < 4; ++s)
#pragma unroll
            for (int i = 0; i < 4; ++i)
#pragma unroll
                for (int t = 0; t < 2; ++t)
                    acc[i * 2 + t] = __builtin_amdgcn_mfma_f32_16x16x32_f16(
                        Ah[i * 4 + s], bh[s * 2 + t], acc[i * 2 + t], 0, 0, 0);
        // pass 2: xl.wh (Al from wave-private LDS; 4 ds_read_b128 per s)
#pragma unroll
        for (int s = 0; s < 4; ++s) {
            f16x8 al[4];
#pragma unroll
            for (int i = 0; i < 4; ++i) al[i] = myAl[(i * 4 + s) * 64 + lane];
#pragma unroll
            for (int i = 0; i < 4; ++i)
#pragma unroll
                for (int t = 0; t < 2; ++t)
                    acc[i * 2 + t] = __builtin_amdgcn_mfma_f32_16x16x32_f16(
                        al[i], bh[s * 2 + t], acc[i * 2 + t], 0, 0, 0);
        }
        // pass 3: xh.wl
#pragma unroll
        for (int s = 0; s < 4; ++s)
#pragma unroll
            for (int i = 0; i < 4; ++i)
#pragma unroll
                for (int t = 0; t < 2; ++t)
                    acc[i * 2 + t] = __builtin_amdgcn_mfma_f32_16x16x32_f16(
                        Ah[i * 4 + s], bl[s * 2 + t], acc[i * 2 + t], 0, 0, 0);

        // ---- score + per-lane argmin. C layout: row m = q*4+r (+16i), col = c (+16t).
#pragma unroll
        for (int t = 0; t < 2; ++t) {
            const int n    = uTile + 16 * t + c;
            const float wq = t == 0 ? wq0 : wq1;
#pragma unroll
            for (int i = 0; i < 4; ++i) {
                f32x4 a = acc[i * 2 + t];
#pragma unroll
                for (int r = 0; r < 4; ++r) {
                    float score = fmaf(-2.f, a[r], wq);
                    int sl = i * 4 + r;
                    if (score < bestD[sl]) { bestD[sl] = score; bestI[sl] = n; }
                }
            }
        }
    }

    // ---- reduce over the 16 col-classes (xor within each 16-lane q-group) ----
#pragma unroll
    for (int sl = 0; sl < 16; ++sl) {
        float d   = bestD[sl];
        int   idx = bestI[sl];
#pragma unroll
        for (int m = 1; m < 16; m <<= 1) {
            float od = __shfl_xor(d, m, 64);
            int   oi = __shfl_xor(idx, m, 64);
            if (od < d || (od == d && oi < idx)) { d = od; idx = oi; }
        }
        if (c == 0) {
            const int sOut = sWave + 16 * (sl >> 2) + 4 * q + (sl & 3);
            if (PARTIAL) {
                unsigned ub = __float_as_uint(d);
                ub = (ub & 0x80000000u) ? ~ub : (ub | 0x80000000u);  // monotone map
                unsigned long long key = ((unsigned long long)ub << 32) | (unsigned)idx;
                keys[(size_t)ug * N + sOut] = key;
            } else {
                out[2 * sOut]     = grid[2 * idx];
                out[2 * sOut + 1] = grid[2 * idx + 1];
            }
        }
    }
}

extern "C" void kernel_launch(void* const* d_in, const int* in_sizes, int n_in,
                              void* d_out, int out_size, void* d_ws, size_t ws_size,
                              hipStream_t stream) {
    const float* x    = (const float*)d_in[0];
    const float* w    = (const float*)d_in[1];
    const int*   grid = (const int*)d_in[2];
    int* out = (int*)d_out;

    const int N = in_sizes[0] / D;   // 32768
    const int M = in_sizes[1] / D;   // 4096

    // ws layout: hG (1 MB) | lG (1 MB) | wsq (16 KB) | keys (UG*N*8)
    const size_t hlBytes   = (size_t)M * D * 2;
    const size_t baseBytes = 2 * hlBytes + (size_t)M * 4;

    f16x8* hG  = (f16x8*)d_ws;
    f16x8* lG  = (f16x8*)((char*)d_ws + hlBytes);
    float* wsq = (float*)((char*)d_ws + 2 * hlBytes);
    unsigned long long* keys = (unsigned long long*)((char*)d_ws + baseBytes);

    prep_kernel<<<(M * 16 + 255) / 256, 256, 0, stream>>>(w, hG, lG, wsq, M);

    const int sampleGroups = N / 256;   // blocks of 4 waves x 64 samples
    int UG = 0;
    if (ws_size >= baseBytes + 4ull * N * 8) UG = 4;
    else if (ws_size >= baseBytes + 2ull * N * 8) UG = 2;

    if (UG > 0) {
        som_main<true><<<sampleGroups * UG, 256, 0, stream>>>(
            x, hG, lG, wsq, grid, out, keys, UG, M, N);
        finalize<<<(N + 255) / 256, 256, 0, stream>>>(keys, grid, out, N, UG);
    } else {
        som_main<false><<<sampleGroups, 256, 0, stream>>>(
            x, hG, lG, wsq, grid, out, nullptr, 1, M, N);
    }
}